// Round 9
// baseline (107.418 us; speedup 1.0000x reference)
//
#include <hip/hip_runtime.h>
#include <math.h>

#define B_ 2
#define T_ 16
#define N_ 128
#define CI 64
#define CO 128

// ws layout (floats):
//   AQ @ 0       : 524288   f4-idx: (((b*8+of)*16+t)*128 + i)*4 + oql   (a + bias)
//   BT @ 524288  : 524288   f4-idx: (((b*8+of)*16+t)*128 + j)*4 + oql   (bpart)
//   CQ @ 1048576 : 4194304  f4-idx: ((b*8+of)*128 + j)*512 + i*4 + oql  (cpart)
#define AQ_OFF 0
#define BT_OFF 524288
#define CQ_OFF 1048576

typedef __attribute__((ext_vector_type(8))) short short8;
typedef __attribute__((ext_vector_type(4))) float f32x4;

__device__ __forceinline__ float4 f4add(float4 a, float4 b) {
  return make_float4(a.x + b.x, a.y + b.y, a.z + b.z, a.w + b.w);
}
__device__ __forceinline__ float4 f4max(float4 a, float4 b) {
  return make_float4(fmaxf(a.x, b.x), fmaxf(a.y, b.y), fmaxf(a.z, b.z), fmaxf(a.w, b.w));
}
__device__ __forceinline__ float4 f4min(float4 a, float4 b) {
  return make_float4(fminf(a.x, b.x), fminf(a.y, b.y), fminf(a.z, b.z), fminf(a.w, b.w));
}
__device__ __forceinline__ void f4fma(float4& acc, float s, float4 v) {
  acc.x = fmaf(s, v.x, acc.x);
  acc.y = fmaf(s, v.y, acc.y);
  acc.z = fmaf(s, v.z, acc.z);
  acc.w = fmaf(s, v.w, acc.w);
}
__device__ __forceinline__ float silu1(float v) { return v / (1.0f + __expf(-v)); }
__device__ __forceinline__ float4 silu4(float4 v) {
  return make_float4(silu1(v.x), silu1(v.y), silu1(v.z), silu1(v.w));
}
__device__ __forceinline__ float4 shfl4x(float4 v, int m) {
  return make_float4(__shfl_xor(v.x, m, 64), __shfl_xor(v.y, m, 64),
                     __shfl_xor(v.z, m, 64), __shfl_xor(v.w, m, 64));
}
__device__ __forceinline__ unsigned int bf2(float a, float b) {
  unsigned int ua = __float_as_uint(a);
  unsigned int ub = __float_as_uint(b);
  ua = (ua + 0x7FFFu + ((ua >> 16) & 1u)) >> 16;
  ub = (ub + 0x7FFFu + ((ub >> 16) & 1u)) >> 16;
  return (ub << 16) | ua;
}
__device__ __forceinline__ uint4 pack8(float4 lo, float4 hi) {
  return make_uint4(bf2(lo.x, lo.y), bf2(lo.z, lo.w), bf2(hi.x, hi.y), bf2(hi.z, hi.w));
}

// =====================================================================
// k_ab3: A/Bp GEMM. grid 512 = b(2) x t(16) x dst(2) x nq(8); 256 thr.
// Stores into the of-major f4 layout consumed by k_red7.
// =====================================================================
__global__ __launch_bounds__(256) void k_ab3(
    const float* __restrict__ x, const float* __restrict__ W,
    const float* __restrict__ bias, float* __restrict__ AQ, float* __restrict__ BT)
{
  __shared__ __align__(16) float WL[64 * 128];  // [c][o]
  __shared__ float xT[64 * 17];                 // [c][n], stride 17

  int blk = blockIdx.x;
  int nq  = blk & 7;
  int dst = (blk >> 3) & 1;
  int t   = (blk >> 4) & 15;
  int b   = blk >> 8;
  float f0 = (t != 0)      ? 1.0f : 0.0f;
  float f2 = (t != T_ - 1) ? 1.0f : 0.0f;
  int tid = threadIdx.x;

  const float4* W4 = (const float4*)W;
  float4* WL4 = (float4*)WL;
  int wb = dst * 6144;                          // dst0: W rows 0..192; dst1: 192..384
  #pragma unroll
  for (int k = 0; k < 8; k++) {
    int idx4 = tid + k * 256;
    float4 wa = W4[wb + idx4];
    float4 wm = W4[wb + 2048 + idx4];
    float4 wc = W4[wb + 4096 + idx4];
    WL4[idx4] = make_float4(f0 * wa.x + wm.x + f2 * wc.x,
                            f0 * wa.y + wm.y + f2 * wc.y,
                            f0 * wa.z + wm.z + f2 * wc.z,
                            f0 * wa.w + wm.w + f2 * wc.w);
  }
  {
    long xb = ((long)(b * T_ + t) * N_ + nq * 16) * CI;
    #pragma unroll
    for (int k = 0; k < 4; k++) {
      int idx = tid + k * 256;
      int c = idx & 63, n = idx >> 6;
      xT[c * 17 + n] = x[xb + n * CI + c];
    }
  }
  __syncthreads();

  int nl = tid & 15;
  int qg = tid >> 4;                            // owns quads 2qg, 2qg+1
  float4 acc0, acc1;
  if (dst == 0) {
    acc0 = ((const float4*)bias)[qg * 2];
    acc1 = ((const float4*)bias)[qg * 2 + 1];
  } else {
    acc0 = make_float4(0, 0, 0, 0); acc1 = acc0;
  }
  #pragma unroll 8
  for (int c = 0; c < 64; c++) {
    float xv = xT[c * 17 + nl];
    float4 w0 = WL4[c * 32 + qg * 2];
    float4 w1 = WL4[c * 32 + qg * 2 + 1];
    f4fma(acc0, xv, w0);
    f4fma(acc1, xv, w1);
  }
  int n = nq * 16 + nl;
  float4* dp4 = (float4*)(dst ? BT : AQ);
  int q0 = qg * 2, q1 = qg * 2 + 1;
  long i0 = (((long)(b * 8 + (q0 >> 2)) * 16 + t) * 128 + n) * 4 + (q0 & 3);
  long i1 = (((long)(b * 8 + (q1 >> 2)) * 16 + t) * 128 + n) * 4 + (q1 & 3);
  dp4[i0] = acc0;
  dp4[i1] = acc1;
}

// =====================================================================
// k_cp4b: Cp via bf16 MFMA (cp4 core). grid 512 = (b, i, jh); 256 thr.
// Store flipped to CQ[b][of][j][i][oq] (64-B segments; writes are cheap).
// =====================================================================
__global__ __launch_bounds__(256) void k_cp4b(
    const float* __restrict__ cond, const float* __restrict__ W,
    float* __restrict__ CQ)
{
  __shared__ __align__(16) unsigned char smem[49152];
  uint4* AF  = (uint4*)smem;             // 1024 frags: [term2][jtl4 x kh2][lane64]
  uint4* WcF = (uint4*)(smem + 16384);   // 2048 frags: [term][kh][ot][lane]
  float* Cp  = (float*)smem;             // overlay: [j 64][o 128] stride 132

  int blk = blockIdx.x;
  int jh = blk & 1;
  int i  = (blk >> 1) & 127;
  int b  = blk >> 8;
  int tid = threadIdx.x;

  // build Wc fragments in-block (from W directly; W is L2-hot read-only)
  #pragma unroll
  for (int f = 0; f < 8; f++) {
    int fid = tid + f * 256;                    // [term2][kh2][ot8][lane64]
    int lane_f = fid & 63;
    int ot   = (fid >> 6) & 7;
    int kh   = (fid >> 9) & 1;
    int term = fid >> 10;
    int o  = ot * 16 + (lane_f & 15);
    int kb = kh * 32 + (lane_f >> 4) * 8;
    float v[8];
    #pragma unroll
    for (int u = 0; u < 8; u++)
      v[u] = W[(384 + term * 64 + kb + u) * 128 + o];
    WcF[fid] = pack8(make_float4(v[0], v[1], v[2], v[3]),
                     make_float4(v[4], v[5], v[6], v[7]));
  }
  // stage A fragments (both terms, this j-half)
  #pragma unroll
  for (int k = 0; k < 4; k++) {
    int idx = tid + k * 256;                    // [term2][jl64][oct8]
    int term = idx >> 9;
    int rem = idx & 511;
    int jl = rem >> 3, oct = rem & 7;
    long row = (term == 0) ? ((long)(b * N_ + i) * N_ + jh * 64 + jl)
                           : ((long)(b * N_ + jh * 64 + jl) * N_ + i);
    const float4* src = (const float4*)(cond + row * 64 + oct * 8);
    float4 lo = src[0], hi = src[1];
    int frag = term * 512 + ((jl >> 4) * 2 + (oct >> 2)) * 64 + (oct & 3) * 16 + (jl & 15);
    AF[frag] = pack8(lo, hi);
  }
  __syncthreads();

  int lane = tid & 63;
  int w    = tid >> 6;
  f32x4 acc[8];
  #pragma unroll
  for (int ot = 0; ot < 8; ot++) {
    acc[ot][0] = 0.f; acc[ot][1] = 0.f; acc[ot][2] = 0.f; acc[ot][3] = 0.f;
  }
  const short8* AF8 = (const short8*)AF;
  const short8* WF8 = (const short8*)WcF;
  #pragma unroll
  for (int term = 0; term < 2; term++) {
    #pragma unroll
    for (int kh = 0; kh < 2; kh++) {
      short8 a = AF8[term * 512 + (w * 2 + kh) * 64 + lane];
      #pragma unroll
      for (int ot = 0; ot < 8; ot++) {
        short8 bv = WF8[((term * 2 + kh) * 8 + ot) * 64 + lane];
        acc[ot] = __builtin_amdgcn_mfma_f32_16x16x32_bf16(a, bv, acc[ot], 0, 0, 0);
      }
    }
  }
  __syncthreads();   // frag reads done; overlay Cp

  // epilogue: acc -> Cp[j_local][o], row stride 132
  {
    int col = lane & 15;
    int row0 = w * 16 + (lane >> 4) * 4;
    #pragma unroll
    for (int ot = 0; ot < 8; ot++) {
      f32x4 d = acc[ot];
      int cbase = ot * 16 + col;
      Cp[(row0 + 0) * 132 + cbase] = d[0];
      Cp[(row0 + 1) * 132 + cbase] = d[1];
      Cp[(row0 + 2) * 132 + cbase] = d[2];
      Cp[(row0 + 3) * 132 + cbase] = d[3];
    }
  }
  __syncthreads();

  // store CQ[b][of][j][i][oq]
  {
    const float4* Cp4 = (const float4*)Cp;      // unit = jl*33 + q (q = of*4+oql)
    float4* CQ4 = (float4*)CQ;
    int oql = tid & 3;
    int jl  = (tid >> 2) & 63;
    #pragma unroll
    for (int of_l = 0; of_l < 8; of_l++) {
      CQ4[(((long)(b * 8 + of_l) * 128) + jh * 64 + jl) * 512 + i * 4 + oql] =
          Cp4[jl * 33 + of_l * 4 + oql];
    }
  }
}

// =====================================================================
// k_red7: out = max(silu(A+mx), silu(A+mn)), mx/mn = max/min_j(Bp+Cp).
// grid 256 = b(2) x of(8) x ih(16, 8 i each); 256 thr = 4 waves.
// BT slice [16t][128j][4oq] = 128 KB staged in LDS once (contiguous).
// Waves split j (w*32 + jh*16): CQ streamed EXACTLY ONCE (no amplification).
// lane = (jh2, il8, oq4); 16-t max/min in registers; jh-shfl + LDS-scratch
// tree combine; silu at interval endpoints (exact, branchless).
// =====================================================================
__global__ __launch_bounds__(256, 1) void k_red7(
    const float* __restrict__ AQ, const float* __restrict__ BT,
    const float* __restrict__ CQ, float* __restrict__ out)
{
  __shared__ __align__(16) float4 BtL[8192];    // 128 KB; reused as scratch

  int blk = blockIdx.x;
  int ih = blk & 15;
  int of = (blk >> 4) & 7;
  int b  = blk >> 7;
  int tid = threadIdx.x;

  const float4* BT4 = (const float4*)BT;
  const float4* CQ4 = (const float4*)CQ;
  const float4* AQ4 = (const float4*)AQ;

  long btbase = (long)(b * 8 + of) * 8192;
  #pragma unroll
  for (int k = 0; k < 32; k++) BtL[tid + k * 256] = BT4[btbase + tid + k * 256];
  __syncthreads();

  int w    = tid >> 6;
  int lane = tid & 63;
  int jh = lane >> 5;
  int il = (lane >> 2) & 7;
  int oq = lane & 3;
  int jb = w * 32 + jh * 16;

  const float4* cq = CQ4 + ((long)(b * 8 + of) * 128) * 512 + (long)(ih * 8 + il) * 4 + oq;

  float4 mx[16], mn[16];
  #pragma unroll
  for (int t = 0; t < 16; t++) {
    mx[t] = make_float4(-3.4e38f, -3.4e38f, -3.4e38f, -3.4e38f);
    mn[t] = make_float4(3.4e38f, 3.4e38f, 3.4e38f, 3.4e38f);
  }

  #pragma unroll
  for (int jj = 0; jj < 16; jj += 4) {
    float4 c0 = cq[(long)(jb + jj + 0) * 512];
    float4 c1 = cq[(long)(jb + jj + 1) * 512];
    float4 c2 = cq[(long)(jb + jj + 2) * 512];
    float4 c3 = cq[(long)(jb + jj + 3) * 512];
    #pragma unroll
    for (int t = 0; t < 16; t++) {
      int bb = (t * 128 + jb + jj) * 4 + oq;
      float4 s0 = f4add(c0, BtL[bb]);
      float4 s1 = f4add(c1, BtL[bb + 4]);
      float4 s2 = f4add(c2, BtL[bb + 8]);
      float4 s3 = f4add(c3, BtL[bb + 12]);
      mx[t] = f4max(mx[t], f4max(f4max(s0, s1), f4max(s2, s3)));
      mn[t] = f4min(mn[t], f4min(f4min(s0, s1), f4min(s2, s3)));
    }
  }

  // combine the two jh-halves in-wave
  #pragma unroll
  for (int t = 0; t < 16; t++) {
    mx[t] = f4max(mx[t], shfl4x(mx[t], 32));
    mn[t] = f4min(mn[t], shfl4x(mn[t], 32));
  }

  __syncthreads();            // all BtL reads complete -> safe to overlay scratch
  float4* scr = BtL;          // mx @ [0,2048), mn @ [2048,4096)
  if (jh == 0) {
    #pragma unroll
    for (int t = 0; t < 16; t++) {
      int sidx = ((w * 16 + t) * 8 + il) * 4 + oq;
      scr[sidx]        = mx[t];
      scr[2048 + sidx] = mn[t];
    }
  }
  __syncthreads();

  // final merge over 4 waves + epilogue; 512 outputs, 2 per thread
  #pragma unroll
  for (int r = 0; r < 2; r++) {
    int oid = tid + r * 256;                    // = t*32 + il*4 + oq
    int t   = oid >> 5;
    int il2 = (oid >> 2) & 7;
    int oq2 = oid & 3;
    int s0 = ((0 * 16 + t) * 8 + il2) * 4 + oq2;
    float4 MX = scr[s0];
    float4 MN = scr[2048 + s0];
    #pragma unroll
    for (int ww = 1; ww < 4; ww++) {
      int si = ((ww * 16 + t) * 8 + il2) * 4 + oq2;
      MX = f4max(MX, scr[si]);
      MN = f4min(MN, scr[2048 + si]);
    }
    float4 av = AQ4[(((long)(b * 8 + of) * 16 + t) * 128 + ih * 8 + il2) * 4 + oq2];
    float4 res = f4max(silu4(f4add(MX, av)), silu4(f4add(MN, av)));
    ((float4*)out)[((long)((b * 16 + t) * 128) + ih * 8 + il2) * 32 + of * 4 + oq2] = res;
  }
}

extern "C" void kernel_launch(void* const* d_in, const int* in_sizes, int n_in,
                              void* d_out, int out_size, void* d_ws, size_t ws_size,
                              hipStream_t stream) {
  const float* x    = (const float*)d_in[0];   // (2,16,128,64)
  const float* cond = (const float*)d_in[1];   // (2,128,128,64)
  const float* W    = (const float*)d_in[2];   // (512,128)
  const float* bias = (const float*)d_in[3];   // (128,)
  float* out = (float*)d_out;                  // (2,16,128,128)

  float* ws = (float*)d_ws;
  float* AQ = ws + AQ_OFF;
  float* BT = ws + BT_OFF;
  float* CQ = ws + CQ_OFF;

  k_ab3<<<512, 256, 0, stream>>>(x, W, bias, AQ, BT);
  k_cp4b<<<512, 256, 0, stream>>>(cond, W, CQ);
  k_red7<<<256, 256, 0, stream>>>(AQ, BT, CQ, out);
}

// Round 10
// 93.961 us; speedup vs baseline: 1.1432x; 1.1432x over previous
//
#include <hip/hip_runtime.h>
#include <math.h>

#define B_ 2
#define T_ 16
#define N_ 128
#define CI 64
#define CO 128

// ws layout (floats):
//   AQ @ 0       : 524288   f4-idx: (((b*8+of)*16+t)*128 + i)*4 + oql   (a + bias)
//   BT @ 524288  : 524288   f4-idx: (((b*8+of)*16+t)*128 + j)*4 + oql   (bpart)
//   CQ @ 1048576 : 4194304  f4-idx: ((b*8+of)*128 + j)*512 + i*4 + oql  (cpart)
#define AQ_OFF 0
#define BT_OFF 524288
#define CQ_OFF 1048576

typedef __attribute__((ext_vector_type(8))) short short8;
typedef __attribute__((ext_vector_type(4))) float f32x4;

__device__ __forceinline__ float4 f4add(float4 a, float4 b) {
  return make_float4(a.x + b.x, a.y + b.y, a.z + b.z, a.w + b.w);
}
__device__ __forceinline__ float4 f4max(float4 a, float4 b) {
  return make_float4(fmaxf(a.x, b.x), fmaxf(a.y, b.y), fmaxf(a.z, b.z), fmaxf(a.w, b.w));
}
__device__ __forceinline__ float4 f4min(float4 a, float4 b) {
  return make_float4(fminf(a.x, b.x), fminf(a.y, b.y), fminf(a.z, b.z), fminf(a.w, b.w));
}
__device__ __forceinline__ void f4fma(float4& acc, float s, float4 v) {
  acc.x = fmaf(s, v.x, acc.x);
  acc.y = fmaf(s, v.y, acc.y);
  acc.z = fmaf(s, v.z, acc.z);
  acc.w = fmaf(s, v.w, acc.w);
}
__device__ __forceinline__ float silu1(float v) { return v / (1.0f + __expf(-v)); }
__device__ __forceinline__ float4 silu4(float4 v) {
  return make_float4(silu1(v.x), silu1(v.y), silu1(v.z), silu1(v.w));
}
__device__ __forceinline__ float4 shfl4x(float4 v, int m) {
  return make_float4(__shfl_xor(v.x, m, 64), __shfl_xor(v.y, m, 64),
                     __shfl_xor(v.z, m, 64), __shfl_xor(v.w, m, 64));
}
__device__ __forceinline__ unsigned int bf2(float a, float b) {
  unsigned int ua = __float_as_uint(a);
  unsigned int ub = __float_as_uint(b);
  ua = (ua + 0x7FFFu + ((ua >> 16) & 1u)) >> 16;
  ub = (ub + 0x7FFFu + ((ub >> 16) & 1u)) >> 16;
  return (ub << 16) | ua;
}
__device__ __forceinline__ uint4 pack8(float4 lo, float4 hi) {
  return make_uint4(bf2(lo.x, lo.y), bf2(lo.z, lo.w), bf2(hi.x, hi.y), bf2(hi.z, hi.w));
}

// =====================================================================
// k_ab3 (verbatim R9, passed): A/Bp GEMM. grid 512; 256 thr.
// =====================================================================
__global__ __launch_bounds__(256) void k_ab3(
    const float* __restrict__ x, const float* __restrict__ W,
    const float* __restrict__ bias, float* __restrict__ AQ, float* __restrict__ BT)
{
  __shared__ __align__(16) float WL[64 * 128];  // [c][o]
  __shared__ float xT[64 * 17];                 // [c][n], stride 17

  int blk = blockIdx.x;
  int nq  = blk & 7;
  int dst = (blk >> 3) & 1;
  int t   = (blk >> 4) & 15;
  int b   = blk >> 8;
  float f0 = (t != 0)      ? 1.0f : 0.0f;
  float f2 = (t != T_ - 1) ? 1.0f : 0.0f;
  int tid = threadIdx.x;

  const float4* W4 = (const float4*)W;
  float4* WL4 = (float4*)WL;
  int wb = dst * 6144;
  #pragma unroll
  for (int k = 0; k < 8; k++) {
    int idx4 = tid + k * 256;
    float4 wa = W4[wb + idx4];
    float4 wm = W4[wb + 2048 + idx4];
    float4 wc = W4[wb + 4096 + idx4];
    WL4[idx4] = make_float4(f0 * wa.x + wm.x + f2 * wc.x,
                            f0 * wa.y + wm.y + f2 * wc.y,
                            f0 * wa.z + wm.z + f2 * wc.z,
                            f0 * wa.w + wm.w + f2 * wc.w);
  }
  {
    long xb = ((long)(b * T_ + t) * N_ + nq * 16) * CI;
    #pragma unroll
    for (int k = 0; k < 4; k++) {
      int idx = tid + k * 256;
      int c = idx & 63, n = idx >> 6;
      xT[c * 17 + n] = x[xb + n * CI + c];
    }
  }
  __syncthreads();

  int nl = tid & 15;
  int qg = tid >> 4;
  float4 acc0, acc1;
  if (dst == 0) {
    acc0 = ((const float4*)bias)[qg * 2];
    acc1 = ((const float4*)bias)[qg * 2 + 1];
  } else {
    acc0 = make_float4(0, 0, 0, 0); acc1 = acc0;
  }
  #pragma unroll 8
  for (int c = 0; c < 64; c++) {
    float xv = xT[c * 17 + nl];
    float4 w0 = WL4[c * 32 + qg * 2];
    float4 w1 = WL4[c * 32 + qg * 2 + 1];
    f4fma(acc0, xv, w0);
    f4fma(acc1, xv, w1);
  }
  int n = nq * 16 + nl;
  float4* dp4 = (float4*)(dst ? BT : AQ);
  int q0 = qg * 2, q1 = qg * 2 + 1;
  long i0 = (((long)(b * 8 + (q0 >> 2)) * 16 + t) * 128 + n) * 4 + (q0 & 3);
  long i1 = (((long)(b * 8 + (q1 >> 2)) * 16 + t) * 128 + n) * 4 + (q1 & 3);
  dp4[i0] = acc0;
  dp4[i1] = acc1;
}

// =====================================================================
// k_cp4b (verbatim R9, passed): Cp via bf16 MFMA. grid 512 = (b,i,jh).
// =====================================================================
__global__ __launch_bounds__(256) void k_cp4b(
    const float* __restrict__ cond, const float* __restrict__ W,
    float* __restrict__ CQ)
{
  __shared__ __align__(16) unsigned char smem[49152];
  uint4* AF  = (uint4*)smem;
  uint4* WcF = (uint4*)(smem + 16384);
  float* Cp  = (float*)smem;

  int blk = blockIdx.x;
  int jh = blk & 1;
  int i  = (blk >> 1) & 127;
  int b  = blk >> 8;
  int tid = threadIdx.x;

  #pragma unroll
  for (int f = 0; f < 8; f++) {
    int fid = tid + f * 256;
    int lane_f = fid & 63;
    int ot   = (fid >> 6) & 7;
    int kh   = (fid >> 9) & 1;
    int term = fid >> 10;
    int o  = ot * 16 + (lane_f & 15);
    int kb = kh * 32 + (lane_f >> 4) * 8;
    float v[8];
    #pragma unroll
    for (int u = 0; u < 8; u++)
      v[u] = W[(384 + term * 64 + kb + u) * 128 + o];
    WcF[fid] = pack8(make_float4(v[0], v[1], v[2], v[3]),
                     make_float4(v[4], v[5], v[6], v[7]));
  }
  #pragma unroll
  for (int k = 0; k < 4; k++) {
    int idx = tid + k * 256;
    int term = idx >> 9;
    int rem = idx & 511;
    int jl = rem >> 3, oct = rem & 7;
    long row = (term == 0) ? ((long)(b * N_ + i) * N_ + jh * 64 + jl)
                           : ((long)(b * N_ + jh * 64 + jl) * N_ + i);
    const float4* src = (const float4*)(cond + row * 64 + oct * 8);
    float4 lo = src[0], hi = src[1];
    int frag = term * 512 + ((jl >> 4) * 2 + (oct >> 2)) * 64 + (oct & 3) * 16 + (jl & 15);
    AF[frag] = pack8(lo, hi);
  }
  __syncthreads();

  int lane = tid & 63;
  int w    = tid >> 6;
  f32x4 acc[8];
  #pragma unroll
  for (int ot = 0; ot < 8; ot++) {
    acc[ot][0] = 0.f; acc[ot][1] = 0.f; acc[ot][2] = 0.f; acc[ot][3] = 0.f;
  }
  const short8* AF8 = (const short8*)AF;
  const short8* WF8 = (const short8*)WcF;
  #pragma unroll
  for (int term = 0; term < 2; term++) {
    #pragma unroll
    for (int kh = 0; kh < 2; kh++) {
      short8 a = AF8[term * 512 + (w * 2 + kh) * 64 + lane];
      #pragma unroll
      for (int ot = 0; ot < 8; ot++) {
        short8 bv = WF8[((term * 2 + kh) * 8 + ot) * 64 + lane];
        acc[ot] = __builtin_amdgcn_mfma_f32_16x16x32_bf16(a, bv, acc[ot], 0, 0, 0);
      }
    }
  }
  __syncthreads();

  {
    int col = lane & 15;
    int row0 = w * 16 + (lane >> 4) * 4;
    #pragma unroll
    for (int ot = 0; ot < 8; ot++) {
      f32x4 d = acc[ot];
      int cbase = ot * 16 + col;
      Cp[(row0 + 0) * 132 + cbase] = d[0];
      Cp[(row0 + 1) * 132 + cbase] = d[1];
      Cp[(row0 + 2) * 132 + cbase] = d[2];
      Cp[(row0 + 3) * 132 + cbase] = d[3];
    }
  }
  __syncthreads();

  {
    const float4* Cp4 = (const float4*)Cp;
    float4* CQ4 = (float4*)CQ;
    int oql = tid & 3;
    int jl  = (tid >> 2) & 63;
    #pragma unroll
    for (int of_l = 0; of_l < 8; of_l++) {
      CQ4[(((long)(b * 8 + of_l) * 128) + jh * 64 + jl) * 512 + i * 4 + oql] =
          Cp4[jl * 33 + of_l * 4 + oql];
    }
  }
}

// =====================================================================
// k_red8: out = max(silu(A+mx), silu(A+mn)), mx/mn = max/min_j(Bp+Cp).
// grid 512 = b(2) x of(8) x th(2) x ih(16); 256 thr = 4 waves.
// BT t-half slab [8t][128j][4oq] = 64 KB LDS -> 2 blocks/CU, 8 waves/CU.
// All 16 CQ loads (512B x 2-segment coalesced) issued UP FRONT (latency
// paid once). lane = (jh2, il8, oq4); waves split j; jh-shfl + LDS-scratch
// tree combine; silu at interval endpoints (exact, branchless).
// =====================================================================
__global__ __launch_bounds__(256, 2) void k_red8(
    const float* __restrict__ AQ, const float* __restrict__ BT,
    const float* __restrict__ CQ, float* __restrict__ out)
{
  __shared__ __align__(16) float4 BtL[4096];    // 64 KB; [tl8][j128][oq4]; reused as scratch

  int blk = blockIdx.x;
  int ih = blk & 15;
  int th = (blk >> 4) & 1;
  int of = (blk >> 5) & 7;
  int b  = blk >> 8;
  int tid = threadIdx.x;

  const float4* BT4 = (const float4*)BT;
  const float4* CQ4 = (const float4*)CQ;
  const float4* AQ4 = (const float4*)AQ;

  long btbase = ((long)(b * 8 + of) * 16 + th * 8) * 512;   // f4 units
  #pragma unroll
  for (int k = 0; k < 16; k++) BtL[tid + k * 256] = BT4[btbase + tid + k * 256];

  int w    = tid >> 6;
  int lane = tid & 63;
  int jh = lane >> 5;
  int il = (lane >> 2) & 7;
  int oq = lane & 3;
  int jb = w * 32 + jh * 16;

  const float4* cq = CQ4 + ((long)(b * 8 + of) * 128) * 512 + (long)(ih * 8 + il) * 4 + oq;

  // issue ALL 16 CQ loads before first use (two 8-reg batches, both in flight)
  float4 c[8], d[8];
  #pragma unroll
  for (int k = 0; k < 8; k++) c[k] = cq[(long)(jb + k) * 512];
  #pragma unroll
  for (int k = 0; k < 8; k++) d[k] = cq[(long)(jb + 8 + k) * 512];

  __syncthreads();   // BtL staged

  float4 mx[8], mn[8];
  #pragma unroll
  for (int t = 0; t < 8; t++) {
    mx[t] = make_float4(-3.4e38f, -3.4e38f, -3.4e38f, -3.4e38f);
    mn[t] = make_float4(3.4e38f, 3.4e38f, 3.4e38f, 3.4e38f);
  }

  #pragma unroll
  for (int k = 0; k < 8; k++) {
    #pragma unroll
    for (int tl = 0; tl < 8; tl++) {
      float4 s = f4add(c[k], BtL[(tl * 128 + jb + k) * 4 + oq]);
      mx[tl] = f4max(mx[tl], s);
      mn[tl] = f4min(mn[tl], s);
    }
  }
  #pragma unroll
  for (int k = 0; k < 8; k++) {
    #pragma unroll
    for (int tl = 0; tl < 8; tl++) {
      float4 s = f4add(d[k], BtL[(tl * 128 + jb + 8 + k) * 4 + oq]);
      mx[tl] = f4max(mx[tl], s);
      mn[tl] = f4min(mn[tl], s);
    }
  }

  // combine jh-halves in-wave (j-coverage: 16 -> 32 per wave)
  #pragma unroll
  for (int tl = 0; tl < 8; tl++) {
    mx[tl] = f4max(mx[tl], shfl4x(mx[tl], 32));
    mn[tl] = f4min(mn[tl], shfl4x(mn[tl], 32));
  }

  __syncthreads();            // BtL reads done -> overlay scratch
  float4* scr = BtL;          // mx @ [0,1024), mn @ [1024,2048)
  if (jh == 0) {
    #pragma unroll
    for (int tl = 0; tl < 8; tl++) {
      int sidx = ((w * 8 + tl) * 8 + il) * 4 + oq;
      scr[sidx]        = mx[tl];
      scr[1024 + sidx] = mn[tl];
    }
  }
  __syncthreads();

  // final merge over 4 waves + epilogue; 256 f4 outputs, 1 per thread
  {
    int tl  = tid >> 5;
    int il2 = (tid >> 2) & 7;
    int oq2 = tid & 3;
    int s0 = (tl * 8 + il2) * 4 + oq2;
    float4 MX = scr[s0];
    float4 MN = scr[1024 + s0];
    #pragma unroll
    for (int ww = 1; ww < 4; ww++) {
      int si = ((ww * 8 + tl) * 8 + il2) * 4 + oq2;
      MX = f4max(MX, scr[si]);
      MN = f4min(MN, scr[1024 + si]);
    }
    int t = th * 8 + tl;
    float4 av = AQ4[(((long)(b * 8 + of) * 16 + t) * 128 + ih * 8 + il2) * 4 + oq2];
    float4 res = f4max(silu4(f4add(MX, av)), silu4(f4add(MN, av)));
    ((float4*)out)[((long)((b * 16 + t) * 128) + ih * 8 + il2) * 32 + of * 4 + oq2] = res;
  }
}

extern "C" void kernel_launch(void* const* d_in, const int* in_sizes, int n_in,
                              void* d_out, int out_size, void* d_ws, size_t ws_size,
                              hipStream_t stream) {
  const float* x    = (const float*)d_in[0];   // (2,16,128,64)
  const float* cond = (const float*)d_in[1];   // (2,128,128,64)
  const float* W    = (const float*)d_in[2];   // (512,128)
  const float* bias = (const float*)d_in[3];   // (128,)
  float* out = (float*)d_out;                  // (2,16,128,128)

  float* ws = (float*)d_ws;
  float* AQ = ws + AQ_OFF;
  float* BT = ws + BT_OFF;
  float* CQ = ws + CQ_OFF;

  k_ab3<<<512, 256, 0, stream>>>(x, W, bias, AQ, BT);
  k_cp4b<<<512, 256, 0, stream>>>(cond, W, CQ);
  k_red8<<<512, 256, 0, stream>>>(AQ, BT, CQ, out);
}